// Round 20
// baseline (500.814 us; speedup 1.0000x reference)
//
#include <hip/hip_runtime.h>

typedef __attribute__((ext_vector_type(4))) int i32x4;

#define NB   32
#define HH   112
#define WW   112
#define CIN  128
#define OH_  110
#define OW_  110
#define COUT 256
#define NCHUNK 18                      // 9 taps x 2 K-halves of 64
#define M_TOTAL (NB * OH_ * OW_)       // 387200
#define BM 128
#define GRID_M (M_TOTAL / BM)          // 3025 exactly, no tail
#define XQ_ELEMS ((long)NB * HH * WW * CIN)   // 51380224
#define NXQB ((unsigned)(XQ_ELEMS / (256 * 16)))   // 12544 x-quant blocks

// ---- fused prep: x fp32 -> int8 (scale 127/6) + weight binarize/pack ----
// blocks [0, NXQB): quantize x. blocks [NXQB, NXQB+72): pack weights.
__global__ void xquant_prep(const float* __restrict__ x, char* __restrict__ xq,
                            const float* __restrict__ kern, char* __restrict__ bq) {
  if (blockIdx.x < NXQB) {
    long i = ((long)blockIdx.x * 256 + threadIdx.x) * 16;
    int w[4];
#pragma unroll
    for (int k = 0; k < 4; ++k) {
      float4 f = *(const float4*)(x + i + k * 4);
      int q0 = (int)rintf(fminf(fmaxf(f.x, -6.f), 6.f) * (127.f / 6.f));
      int q1 = (int)rintf(fminf(fmaxf(f.y, -6.f), 6.f) * (127.f / 6.f));
      int q2 = (int)rintf(fminf(fmaxf(f.z, -6.f), 6.f) * (127.f / 6.f));
      int q3 = (int)rintf(fminf(fmaxf(f.w, -6.f), 6.f) * (127.f / 6.f));
      w[k] = (q0 & 255) | ((q1 & 255) << 8) | ((q2 & 255) << 16) | (q3 << 24);
    }
    *(i32x4*)(xq + i) = (i32x4){w[0], w[1], w[2], w[3]};
    return;
  }
  // weights: 16B slot = ((chunk*2 + nh)*8 + nb)*64 + lane (16 KB/chunk, N=256)
  // byte j: n = nh*128 + nb*16 + (lane&15); ci = (chunk&1)*64 + (lane>>4)*16 + j
  int idx = (int)(blockIdx.x - NXQB) * 256 + threadIdx.x;   // 18432 total
  if (idx >= NCHUNK * 2 * 8 * 64) return;
  int lane  = idx & 63;
  int nb    = (idx >> 6) & 7;
  int nh    = (idx >> 9) & 1;
  int chunk = idx >> 10;
  int tap   = chunk >> 1;
  int n     = nh * 128 + nb * 16 + (lane & 15);
  int cib   = (chunk & 1) * 64 + ((lane >> 4) << 4);
  int w[4] = {0, 0, 0, 0};
#pragma unroll
  for (int j = 0; j < 16; ++j) {
    float kv = kern[(tap * CIN + cib + j) * COUT + n];
    float hs = fminf(fmaxf((kv + 1.0f) * 0.5f, 0.0f), 1.0f);
    int b = (rintf(hs) > 0.5f) ? 1 : -1;   // round-half-even like jnp.round
    w[j >> 2] |= (b & 255) << ((j & 3) * 8);
  }
  *(i32x4*)(bq + (long)idx * 16) = (i32x4){w[0], w[1], w[2], w[3]};
}

__device__ __forceinline__ void gload16(const char* g, char* l) {
  __builtin_amdgcn_global_load_lds(
      (const __attribute__((address_space(1))) unsigned int*)g,
      (__attribute__((address_space(3))) unsigned int*)l, 16, 0, 0);
}

#define BAR() __builtin_amdgcn_s_barrier()

// ==== int8, BM=128 x BN=256, 512 thr (2m x 4n waves of 64x64);
// A 2-ring (16 KB, staged once — no nh dup) + B 2-ring (32 KB) = 48 KB LDS
// -> 3 blocks/CU = 24 waves/CU (1.5x R17 TLP). vmcnt(0) boundaries (depth-1
// prefetch, R13-safe pattern). NT stores. =====================================
__global__ __launch_bounds__(512, 6) void bconv(
    const char* __restrict__ xq, const char* __restrict__ bq,
    const float* __restrict__ bias, float* __restrict__ out) {
  extern __shared__ char lds[];
  // A slots: 0, 8192 (128 rows x 64 B, kq-XOR-swizzled content)
  // B slots: 16384, 32768 (16 KB each, fragment-linear, full N=256)

  const int tid  = threadIdx.x;
  const int lane = tid & 63;
  const int wave = tid >> 6;
  const int wm   = wave >> 2;   // 0..1 (64-row half)
  const int wn   = wave & 3;    // 0..3 (64-col band)

  // bijective XCD-chunked swizzle (m204) over 3025 M-blocks
  const int q = GRID_M >> 3, r = GRID_M & 7;
  const int xcd = (int)blockIdx.x & 7, ob = (int)blockIdx.x >> 3;
  const int bid = (xcd < r ? xcd * (q + 1) : r * (q + 1) + (xcd - r) * q) + ob;
  const long m0 = (long)bid * BM;

  // ---- A staging (pre-swizzled source, rule #21): thread covers row tid>>2,
  //      dest quarter tid&3 holds source quarter (tid&3)^(row&3). 1 gload/thr.
  const int kqsrc = (((tid & 3) ^ ((tid >> 2) & 3)) << 4);
  long rbase;
  {
    long mrow = m0 + (tid >> 2);                   // < M_TOTAL (exact tiling)
    int nimg = (int)(mrow / (OH_ * OW_));
    int r2   = (int)(mrow - (long)nimg * (OH_ * OW_));
    int oh   = r2 / OW_;
    int ow   = r2 - oh * OW_;
    rbase = (((long)nimg * HH + oh) * WW + ow) * CIN + kqsrc;
  }
  const int adst = tid * 16;

#define STAGE_A(aoff, cN) do {                                               \
    const int t_ = (cN) >> 1;                                                \
    const long xo_ = (long)((t_ / 3) * WW + (t_ % 3)) * CIN + ((cN) & 1) * 64; \
    gload16(xq + rbase + xo_, lds + (aoff) + adst);                          \
  } while (0)

#define STAGE_B(boff, cN) do {                                               \
    const char* bs_ = bq + (long)(cN) * 16384 + adst;                        \
    gload16(bs_,        lds + (boff) + adst);                                \
    gload16(bs_ + 8192, lds + (boff) + adst + 8192);                         \
  } while (0)

  // ---- fragment read addressing ----
  // A: row = wm*64 + mi*16 + (lane&15); addr = row*64 + ((lane>>4)^(row&3))*16;
  //    row&3 == lane&3 -> constant per thread. (Measured 0-conflict.)
  const int arow = (wm * 64 + (lane & 15)) * 64;    // + mi*1024 + kqrd
  const int kqrd = (((lane >> 4) ^ (lane & 3)) << 4);
  const int brd  = (wn * 4) * 1024 + lane * 16;     // + ni*1024

  i32x4 acc[4][4];
#pragma unroll
  for (int i = 0; i < 4; ++i)
#pragma unroll
    for (int j = 0; j < 4; ++j) acc[i][j] = (i32x4){0, 0, 0, 0};

  // ---- prologue: A(0)+B(0) landed before first use ----
  STAGE_A(0, 0);
  STAGE_B(16384, 0);
  asm volatile("s_waitcnt vmcnt(0)" ::: "memory");
  BAR();

  int a0 = 0, a1 = 8192;
  int b0 = 16384, b1 = 32768;
#pragma unroll 1
  for (int c = 0; c < NCHUNK; ++c) {
    // prefetch next chunk into inactive slots (no reader this chunk)
    if (c + 1 < NCHUNK) { STAGE_A(a1, c + 1); STAGE_B(b1, c + 1); }

    i32x4 af[4], bf[4];
#pragma unroll
    for (int mi = 0; mi < 4; ++mi)
      af[mi] = *(const i32x4*)(lds + a0 + arow + mi * 1024 + kqrd);
#pragma unroll
    for (int ni = 0; ni < 4; ++ni)
      bf[ni] = *(const i32x4*)(lds + b0 + brd + ni * 1024);
#pragma unroll
    for (int mi = 0; mi < 4; ++mi)
#pragma unroll
      for (int ni = 0; ni < 4; ++ni)
        acc[mi][ni] = __builtin_amdgcn_mfma_i32_16x16x64_i8(af[mi], bf[ni], acc[mi][ni], 0, 0, 0);

    // boundary: drain this chunk's prefetch (issued a full chunk ago), swap.
    // Reads of a0/b0 were consumed by the MFMAs above (compiler lgkm waits),
    // so overwriting them next chunk after the barrier is safe (R13 pattern).
    if (c + 1 < NCHUNK) {
      asm volatile("s_waitcnt vmcnt(0)" ::: "memory");
      BAR();
      int t = a0; a0 = a1; a1 = t;
      int u = b0; b0 = b1; b1 = u;
    }
  }
#undef STAGE_A
#undef STAGE_B

  // ---- Epilogue: NT stores (output never re-read; keep L2 for xq/bq) ----
  const float S = 6.f / 127.f;
  const int  colb = wn * 64 + (lane & 15);
  const long rowb = m0 + wm * 64 + ((lane >> 4) << 2);
#pragma unroll
  for (int ni = 0; ni < 4; ++ni) {
    const int col = colb + ni * 16;
    const float bv = bias[col];
#pragma unroll
    for (int mi = 0; mi < 4; ++mi)
#pragma unroll
      for (int rr = 0; rr < 4; ++rr)
        __builtin_nontemporal_store((float)acc[mi][ni][rr] * S + bv,
                                    &out[(rowb + mi * 16 + rr) * COUT + col]);
  }
}

extern "C" void kernel_launch(void* const* d_in, const int* in_sizes, int n_in,
                              void* d_out, int out_size, void* d_ws, size_t ws_size,
                              hipStream_t stream) {
  const float* x    = (const float*)d_in[0];
  const float* kern = (const float*)d_in[1];
  const float* bias = (const float*)d_in[2];
  float* out = (float*)d_out;

  char* xq = (char*)d_ws;                                  // 51380224 B
  char* bq = (char*)d_ws + XQ_ELEMS;                       // 294912 B

  (void)hipFuncSetAttribute((const void*)bconv,
                            hipFuncAttributeMaxDynamicSharedMemorySize, 49152);

  xquant_prep<<<dim3(NXQB + 72), dim3(256), 0, stream>>>(x, xq, kern, bq);
  bconv<<<dim3(GRID_M), dim3(512), 49152, stream>>>(xq, bq, bias, out);
}

// Round 21
// 174.166 us; speedup vs baseline: 2.8755x; 2.8755x over previous
//
#include <hip/hip_runtime.h>

typedef __attribute__((ext_vector_type(4))) int i32x4;

#define NB   32
#define HH   112
#define WW   112
#define CIN  128
#define OH_  110
#define OW_  110
#define COUT 256
#define NCHUNK 18                      // 9 taps x 2 K-halves of 64
#define M_TOTAL (NB * OH_ * OW_)       // 387200
#define BM 128
#define GRID_M (M_TOTAL / BM)          // 3025 exactly, no tail
#define XQ_ELEMS ((long)NB * HH * WW * CIN)   // 51380224
#define NXQB ((unsigned)(XQ_ELEMS / (256 * 16)))   // 12544 x-quant blocks

// ---- fused prep: x fp32 -> int8 (scale 127/6) + weight binarize/pack ----
// blocks [0, NXQB): quantize x. blocks [NXQB, NXQB+72): pack weights.
__global__ void xquant_prep(const float* __restrict__ x, char* __restrict__ xq,
                            const float* __restrict__ kern, char* __restrict__ bq) {
  if (blockIdx.x < NXQB) {
    long i = ((long)blockIdx.x * 256 + threadIdx.x) * 16;
    int w[4];
#pragma unroll
    for (int k = 0; k < 4; ++k) {
      float4 f = *(const float4*)(x + i + k * 4);
      int q0 = (int)rintf(fminf(fmaxf(f.x, -6.f), 6.f) * (127.f / 6.f));
      int q1 = (int)rintf(fminf(fmaxf(f.y, -6.f), 6.f) * (127.f / 6.f));
      int q2 = (int)rintf(fminf(fmaxf(f.z, -6.f), 6.f) * (127.f / 6.f));
      int q3 = (int)rintf(fminf(fmaxf(f.w, -6.f), 6.f) * (127.f / 6.f));
      w[k] = (q0 & 255) | ((q1 & 255) << 8) | ((q2 & 255) << 16) | (q3 << 24);
    }
    *(i32x4*)(xq + i) = (i32x4){w[0], w[1], w[2], w[3]};
    return;
  }
  // weights: 16B slot = ((chunk*2 + nh)*8 + nb)*64 + lane (16 KB/chunk, N=256)
  // byte j: n = nh*128 + nb*16 + (lane&15); ci = (chunk&1)*64 + (lane>>4)*16 + j
  int idx = (int)(blockIdx.x - NXQB) * 256 + threadIdx.x;   // 18432 total
  if (idx >= NCHUNK * 2 * 8 * 64) return;
  int lane  = idx & 63;
  int nb    = (idx >> 6) & 7;
  int nh    = (idx >> 9) & 1;
  int chunk = idx >> 10;
  int tap   = chunk >> 1;
  int n     = nh * 128 + nb * 16 + (lane & 15);
  int cib   = (chunk & 1) * 64 + ((lane >> 4) << 4);
  int w[4] = {0, 0, 0, 0};
#pragma unroll
  for (int j = 0; j < 16; ++j) {
    float kv = kern[(tap * CIN + cib + j) * COUT + n];
    float hs = fminf(fmaxf((kv + 1.0f) * 0.5f, 0.0f), 1.0f);
    int b = (rintf(hs) > 0.5f) ? 1 : -1;   // round-half-even like jnp.round
    w[j >> 2] |= (b & 255) << ((j & 3) * 8);
  }
  *(i32x4*)(bq + (long)idx * 16) = (i32x4){w[0], w[1], w[2], w[3]};
}

__device__ __forceinline__ void gload16(const char* g, char* l) {
  __builtin_amdgcn_global_load_lds(
      (const __attribute__((address_space(1))) unsigned int*)g,
      (__attribute__((address_space(3))) unsigned int*)l, 16, 0, 0);
}

#define BAR() __builtin_amdgcn_s_barrier()

// ==== R17 champion: int8, BM=128 x BN=256, 512 thr (2m x 4n waves of 64x64);
// A 2-ring (16 KB, staged once — no nh dup), B 3-ring (48 KB); 64 KB LDS ->
// 2 blocks/CU = 16 waves/CU (register wall: ~60 VGPR + 64 AGPR acc/thread).
// Loose 1-barrier/chunk schedule, counted vmcnt(2) boundaries, NT stores. ====
__global__ __launch_bounds__(512, 2) void bconv(
    const char* __restrict__ xq, const char* __restrict__ bq,
    const float* __restrict__ bias, float* __restrict__ out) {
  extern __shared__ char lds[];
  // A slots: 0, 8192 (128 rows x 64 B, kq-XOR-swizzled content)
  // B slots: 16384, 32768, 49152 (16 KB each, fragment-linear, full N=256)

  const int tid  = threadIdx.x;
  const int lane = tid & 63;
  const int wave = tid >> 6;
  const int wm   = wave >> 2;   // 0..1 (64-row half)
  const int wn   = wave & 3;    // 0..3 (64-col band)

  // bijective XCD-chunked swizzle (m204) over 3025 M-blocks
  const int q = GRID_M >> 3, r = GRID_M & 7;
  const int xcd = (int)blockIdx.x & 7, ob = (int)blockIdx.x >> 3;
  const int bid = (xcd < r ? xcd * (q + 1) : r * (q + 1) + (xcd - r) * q) + ob;
  const long m0 = (long)bid * BM;

  // ---- A staging (pre-swizzled source, rule #21): thread covers row tid>>2,
  //      dest quarter tid&3 holds source quarter (tid&3)^(row&3). 1 gload/thr.
  const int kqsrc = (((tid & 3) ^ ((tid >> 2) & 3)) << 4);
  long rbase;
  {
    long mrow = m0 + (tid >> 2);                   // < M_TOTAL (exact tiling)
    int nimg = (int)(mrow / (OH_ * OW_));
    int r2   = (int)(mrow - (long)nimg * (OH_ * OW_));
    int oh   = r2 / OW_;
    int ow   = r2 - oh * OW_;
    rbase = (((long)nimg * HH + oh) * WW + ow) * CIN + kqsrc;
  }
  const int adst = tid * 16;

#define STAGE_A(aoff, cN) do {                                               \
    const int t_ = (cN) >> 1;                                                \
    const long xo_ = (long)((t_ / 3) * WW + (t_ % 3)) * CIN + ((cN) & 1) * 64; \
    gload16(xq + rbase + xo_, lds + (aoff) + adst);                          \
  } while (0)

#define STAGE_B(boff, cN) do {                                               \
    const char* bs_ = bq + (long)(cN) * 16384 + adst;                        \
    gload16(bs_,        lds + (boff) + adst);                                \
    gload16(bs_ + 8192, lds + (boff) + adst + 8192);                         \
  } while (0)

  // ---- fragment read addressing ----
  // A: row = wm*64 + mi*16 + (lane&15); addr = row*64 + ((lane>>4)^(row&3))*16;
  //    row&3 == lane&3 -> constant per thread. (Measured 0-conflict.)
  const int arow = (wm * 64 + (lane & 15)) * 64;    // + mi*1024 + kqrd
  const int kqrd = (((lane >> 4) ^ (lane & 3)) << 4);
  const int brd  = (wn * 4) * 1024 + lane * 16;     // + ni*1024

  i32x4 acc[4][4];
#pragma unroll
  for (int i = 0; i < 4; ++i)
#pragma unroll
    for (int j = 0; j < 4; ++j) acc[i][j] = (i32x4){0, 0, 0, 0};

  // ---- prologue: A(0)+B(0) landed; B(1)'s 2 loads stay in flight ----
  STAGE_A(0, 0);
  STAGE_B(16384, 0);
  STAGE_B(32768, 1);
  asm volatile("s_waitcnt vmcnt(2)" ::: "memory");
  BAR();

  int a0 = 0, a1 = 8192;
  int b0 = 16384, b1 = 32768, b2 = 49152;
#pragma unroll 1
  for (int c = 0; c < NCHUNK; ++c) {
    // prefetch to inactive slots (no reader this chunk)
    if (c + 1 < NCHUNK) STAGE_A(a1, c + 1);
    if (c + 2 < NCHUNK) STAGE_B(b2, c + 2);

    i32x4 af[4], bf[4];
#pragma unroll
    for (int mi = 0; mi < 4; ++mi)
      af[mi] = *(const i32x4*)(lds + a0 + arow + mi * 1024 + kqrd);
#pragma unroll
    for (int ni = 0; ni < 4; ++ni)
      bf[ni] = *(const i32x4*)(lds + b0 + brd + ni * 1024);
#pragma unroll
    for (int mi = 0; mi < 4; ++mi)
#pragma unroll
      for (int ni = 0; ni < 4; ++ni)
        acc[mi][ni] = __builtin_amdgcn_mfma_i32_16x16x64_i8(af[mi], bf[ni], acc[mi][ni], 0, 0, 0);

    // boundary: FIFO = B(c+1)x2, A(c+1)x1, B(c+2)x2 -> vmcnt(2) drains first 3
    if (c < NCHUNK - 2)       asm volatile("s_waitcnt vmcnt(2)" ::: "memory");
    else if (c == NCHUNK - 2) asm volatile("s_waitcnt vmcnt(0)" ::: "memory");
    BAR();
    int t = a0; a0 = a1; a1 = t;
    int u = b0; b0 = b1; b1 = b2; b2 = u;
  }
#undef STAGE_A
#undef STAGE_B

  // ---- Epilogue: NT stores (output never re-read; keep L2 for xq/bq) ----
  const float S = 6.f / 127.f;
  const int  colb = wn * 64 + (lane & 15);
  const long rowb = m0 + wm * 64 + ((lane >> 4) << 2);
#pragma unroll
  for (int ni = 0; ni < 4; ++ni) {
    const int col = colb + ni * 16;
    const float bv = bias[col];
#pragma unroll
    for (int mi = 0; mi < 4; ++mi)
#pragma unroll
      for (int rr = 0; rr < 4; ++rr)
        __builtin_nontemporal_store((float)acc[mi][ni][rr] * S + bv,
                                    &out[(rowb + mi * 16 + rr) * COUT + col]);
  }
}

extern "C" void kernel_launch(void* const* d_in, const int* in_sizes, int n_in,
                              void* d_out, int out_size, void* d_ws, size_t ws_size,
                              hipStream_t stream) {
  const float* x    = (const float*)d_in[0];
  const float* kern = (const float*)d_in[1];
  const float* bias = (const float*)d_in[2];
  float* out = (float*)d_out;

  char* xq = (char*)d_ws;                                  // 51380224 B
  char* bq = (char*)d_ws + XQ_ELEMS;                       // 294912 B

  (void)hipFuncSetAttribute((const void*)bconv,
                            hipFuncAttributeMaxDynamicSharedMemorySize, 65536);

  xquant_prep<<<dim3(NXQB + 72), dim3(256), 0, stream>>>(x, xq, kern, bq);
  bconv<<<dim3(GRID_M), dim3(512), 65536, stream>>>(xq, bq, bias, out);
}